// Round 4
// baseline (791.985 us; speedup 1.0000x reference)
//
#include <hip/hip_runtime.h>

#define D 256
#define SH 16
#define Ss 4
#define CH 256          // nodes per chunk (one block per chunk)
#define NT 64           // nodes per LDS tile
#define XS_STRIDE 272   // f16 per row (544 B); data in e<256, pad 256..271
#define WB_STRIDE 80    // f16 per row (160 B)

typedef _Float16 half8 __attribute__((ext_vector_type(8)));
typedef _Float16 half4 __attribute__((ext_vector_type(4)));
typedef float f32x4 __attribute__((ext_vector_type(4)));

// workspace layout (bytes)
#define OFF_AF16   ((size_t)0)         // a_f16[16][256]            8192
#define OFF_CM     ((size_t)8192)      // CM[16] f32 (= -6*||a||)
#define OFF_DONE   ((size_t)8448)      // int done[256] per-graph chunk counters
#define OFF_DESC   ((size_t)12544)     // int nchunks (+pad16), int4 desc[<=1295]
#define OFF_SUMEXP ((size_t)33280)     // [256][16] f32             16384
#define OFF_ACC    ((size_t)49664)     // [256][16][256] f32        4194304
#define OFF_WVT    ((size_t)4243968)   // WvT[256][256]
#define OFF_WOT    ((size_t)4506112)   // WoT[256][256]
#define OFF_FC1T   ((size_t)4768256)   // fc1T[1024][256]
#define OFF_FC2T   ((size_t)5816832)   // fc2T[256][256]

#define SMEM_BYTES (NT * XS_STRIDE * 2 + SH * WB_STRIDE * 2)   // 37376 B

// ---------- K0: fused prep — zero + weight transposes + a/cm + chunk descriptors ----
__global__ void k_pre(const float* __restrict__ seeds,
                      const float* __restrict__ inw,
                      const float* __restrict__ inb,
                      const int* __restrict__ counts,
                      const float* __restrict__ ow,
                      const float* __restrict__ f1w,
                      const float* __restrict__ f2w,
                      char* __restrict__ ws) {
  __shared__ __align__(16) char smem[4352];
  const int t = threadIdx.x;
  const int b = blockIdx.x;

  // zero sumexp + acc (ordered before k_main by dispatch boundary)
  {
    f32x4* z = (f32x4*)(ws + OFF_SUMEXP);
    const int total4 = (16384 + 4194304) / 16;
    f32x4 zero = {0.f, 0.f, 0.f, 0.f};
    for (int i = b * 256 + t; i < total4; i += 512 * 256) z[i] = zero;
  }

  if (b < 448) {
    // ---- weight transposes (coalesced epilogue reads) ----
    const float* src; float* dst; int R, C, ti, tj;
    if (b < 64)       { src = inw + (size_t)512 * D; dst = (float*)(ws + OFF_WVT);  R = 256; C = 256;  int x = b;       tj = x / 8; ti = x % 8; }
    else if (b < 128) { src = ow;                    dst = (float*)(ws + OFF_WOT);  R = 256; C = 256;  int x = b - 64;  tj = x / 8; ti = x % 8; }
    else if (b < 192) { src = f2w;                   dst = (float*)(ws + OFF_FC2T); R = 256; C = 256;  int x = b - 128; tj = x / 8; ti = x % 8; }
    else              { src = f1w;                   dst = (float*)(ws + OFF_FC1T); R = 256; C = 1024; int x = b - 192; tj = x / 8; ti = x % 8; }
    float (*tl)[33] = (float(*)[33])smem;
    int tx = t & 31, ty = t >> 5;   // 32 x 8
    #pragma unroll
    for (int k = 0; k < 4; k++) {
      int r = ty + k * 8;
      tl[r][tx] = src[(size_t)(ti * 32 + r) * C + tj * 32 + tx];
    }
    __syncthreads();
    #pragma unroll
    for (int k = 0; k < 4; k++) {
      int r = ty + k * 8;
      dst[(size_t)(tj * 32 + r) * R + ti * 32 + tx] = tl[tx][r];
    }
  } else if (b < 464) {
    // ---- a[sh] = 0.125 * q_sh @ Wk_h ; CM[sh] = -6*||a||  (q computed inline) ----
    int sh = b - 448, s = sh >> 2, h = sh & 3;
    float* sd   = (float*)smem;     // seeds row s          [256]
    float* part = sd + 256;         // q partials [4][64]
    float* qh   = part + 256;       // q head slice          [64]
    float* red  = qh + 64;          // reduction             [256]
    sd[t] = seeds[s * D + t];
    __syncthreads();
    int j = t & 63, p = t >> 6;
    const float4* wq = (const float4*)(inw + (size_t)(h * 64 + j) * D + p * 64);
    float pa = 0.f;
    #pragma unroll
    for (int k4 = 0; k4 < 16; k4++) {
      float4 w4 = wq[k4];
      pa += w4.x * sd[p*64 + 4*k4] + w4.y * sd[p*64 + 4*k4 + 1]
          + w4.z * sd[p*64 + 4*k4 + 2] + w4.w * sd[p*64 + 4*k4 + 3];
    }
    part[p * 64 + j] = pa;
    __syncthreads();
    if (t < 64) qh[t] = part[t] + part[64 + t] + part[128 + t] + part[192 + t] + inb[h * 64 + t];
    __syncthreads();
    const float* wk = inw + (size_t)(D + h * 64) * D;   // Wk rows for head h
    float a = 0.f;
    #pragma unroll 8
    for (int d = 0; d < 64; d++) a += qh[d] * wk[(size_t)d * D + t];
    a *= 0.125f;
    ((_Float16*)(ws + OFF_AF16))[sh * D + t] = (_Float16)a;
    red[t] = a * a;
    __syncthreads();
    for (int st = 128; st > 0; st >>= 1) { if (t < st) red[t] += red[t + st]; __syncthreads(); }
    if (t == 0) ((float*)(ws + OFF_CM))[sh] = -6.0f * sqrtf(red[0]);
  } else if (b == 464) {
    // ---- chunk descriptors (+ done-counter zeroing) ----
    ((int*)(ws + OFF_DONE))[t] = 0;
    int* s1 = (int*)smem;
    int* s2 = s1 + 256;
    int cnt = counts[t];
    int nch = (cnt + CH - 1) / CH;
    s1[t] = cnt; s2[t] = nch;
    __syncthreads();
    for (int off = 1; off < 256; off <<= 1) {
      int a1 = (t >= off) ? s1[t - off] : 0;
      int a2 = (t >= off) ? s2[t - off] : 0;
      __syncthreads();
      s1[t] += a1; s2[t] += a2;
      __syncthreads();
    }
    int start = s1[t] - cnt, cb = s2[t] - nch;
    int4* desc = (int4*)(ws + OFF_DESC + 16);
    for (int jj = 0; jj < nch; jj++) {
      int nn = cnt - jj * CH; if (nn > CH) nn = CH;
      desc[cb + jj] = make_int4(t, start + jj * CH, nn, nch);
    }
    if (t == 255) *(int*)(ws + OFF_DESC) = s2[255];
  }
}

// ---------- K1: main sweep + fused per-graph finalize (split-K semaphore) ----------
// LDS swizzle: within-row f16 offset e (e<256) stored at e ^ (((row>>3)&3)<<4)
// -> accumulate gather (rows 8 apart, same dd) is bank-conflict-free.
// T14 pipeline: tile t+1's 16 global_load_dwordx4 issued during tile t's LDS write,
// stay in flight across score+accumulate; waited at next iteration's convert+write.
// Finalize: last chunk-block of graph g (done[g] counter) runs the full epilogue.
__launch_bounds__(256, 3)
__global__ void k_main(const float* __restrict__ nf,
                       const float* __restrict__ inb, const float* __restrict__ ob,
                       const float* __restrict__ f1b, const float* __restrict__ f2b,
                       char* __restrict__ ws, float* __restrict__ out) {
  __shared__ __align__(16) char smem[SMEM_BYTES];
  __shared__ int lastflag;
  int nchunks = *(const int*)(ws + OFF_DESC);
  if ((int)blockIdx.x >= nchunks) return;
  int4 dsc = ((const int4*)(ws + OFF_DESC + 16))[blockIdx.x];
  const int g = dsc.x, start = dsc.y, cnt = dsc.z, nch = dsc.w;

  _Float16* xs = (_Float16*)smem;                            // [NT][XS_STRIDE]
  _Float16* wb = (_Float16*)(smem + NT * XS_STRIDE * 2);     // [SH][WB_STRIDE]

  const int t = threadIdx.x;
  const int lane = t & 63, wv = t >> 6;
  const int col = lane & 15, q = lane >> 4;

  // persistent B-frags of a (score GEMM), 32 VGPRs
  const _Float16* af = (const _Float16*)(ws + OFF_AF16);
  half8 aw[8];
  #pragma unroll
  for (int kc = 0; kc < 8; kc++) aw[kc] = *(const half8*)(af + col * D + kc * 32 + q * 8);
  const float cmv = ((const float*)(ws + OFF_CM))[col];

  f32x4 acc[4] = {{0,0,0,0},{0,0,0,0},{0,0,0,0},{0,0,0,0}};  // [sh(4 rows)] x d-slice
  float dsum = 0.f;

  const int ntile = (cnt + NT - 1) / NT;
  float4 vr[16];

  // prologue: stage tile 0 into regs (row = p*4+wv, c4 = lane)
  #pragma unroll
  for (int p = 0; p < 16; p++) {
    int row = p * 4 + wv;
    vr[p] = make_float4(0.f, 0.f, 0.f, 0.f);
    if (row < cnt) vr[p] = ((const float4*)(nf + (size_t)(start + row) * D))[lane];
  }

  for (int tile = 0; tile < ntile; tile++) {
    const bool more = (tile + 1) < ntile;
    const int nbase = (tile + 1) * NT;
    // ---- convert + write tile t, immediately re-issue loads for tile t+1 ----
    #pragma unroll
    for (int p = 0; p < 16; p++) {
      int row = p * 4 + wv;
      float4 v = vr[p];
      half4 hv;
      hv[0] = (_Float16)v.x; hv[1] = (_Float16)v.y;
      hv[2] = (_Float16)v.z; hv[3] = (_Float16)v.w;
      int e = (lane * 4) ^ (((row >> 3) & 3) << 4);
      *(half4*)(xs + row * XS_STRIDE + e) = hv;
      if (more) {
        int nloc = nbase + row;
        vr[p] = make_float4(0.f, 0.f, 0.f, 0.f);
        if (nloc < cnt) vr[p] = ((const float4*)(nf + (size_t)(start + nloc) * D))[lane];
      }
    }
    __syncthreads();

    // ---- scores: S[16n x 16sh] per wave (wave w owns nodes w*16..+15) ----
    f32x4 sc = {0, 0, 0, 0};
    {
      int srow = wv * 16 + col;
      const _Float16* xrow = xs + srow * XS_STRIDE;
      int sxor = ((srow >> 3) & 3) << 4;
      #pragma unroll
      for (int kc = 0; kc < 8; kc++) {
        half8 xa = *(const half8*)(xrow + ((q * 8 + kc * 32) ^ sxor));
        sc = __builtin_amdgcn_mfma_f32_16x16x32_f16(xa, aw[kc], sc, 0, 0, 0);
      }
    }
    #pragma unroll
    for (int r = 0; r < 4; r++) {
      int nloc = wv * 16 + q * 4 + r;
      float arg = fminf(sc[r] + cmv, 10.f);
      float wj = (tile * NT + nloc < cnt) ? __expf(arg) : 0.f;
      _Float16 wh = (_Float16)wj;
      dsum += (float)wh;                    // denominator consistent with f16 numerator
      wb[col * WB_STRIDE + nloc] = wh;
    }
    __syncthreads();

    // ---- accumulate: acc[16sh x 64d-slice per wave] += w^T @ X ----
    // gather row = ks*32+q*8+jj -> ((row>>3)&3) == q -> xor is q<<4 (conflict-free)
    #pragma unroll
    for (int ks = 0; ks < 2; ks++) {
      half8 wa = *(const half8*)(wb + col * WB_STRIDE + ks * 32 + q * 8);
      #pragma unroll
      for (int dt = 0; dt < 4; dt++) {
        int dd = (wv * 64 + dt * 16 + col) ^ (q << 4);
        half8 xb;
        #pragma unroll
        for (int jj = 0; jj < 8; jj++) xb[jj] = xs[(ks * 32 + q * 8 + jj) * XS_STRIDE + dd];
        acc[dt] = __builtin_amdgcn_mfma_f32_16x16x32_f16(wa, xb, acc[dt], 0, 0, 0);
      }
    }
    __syncthreads();
  }

  // ---- chunk epilogue: denominators + weighted sums via device atomics ----
  dsum += __shfl_xor(dsum, 16);
  dsum += __shfl_xor(dsum, 32);
  if (q == 0) atomicAdd(((float*)(ws + OFF_SUMEXP)) + g * SH + col, dsum);
  float* accw = (float*)(ws + OFF_ACC);
  #pragma unroll
  for (int dt = 0; dt < 4; dt++)
    #pragma unroll
    for (int r = 0; r < 4; r++)
      atomicAdd(&accw[(size_t)(g * SH + q * 4 + r) * D + wv * 64 + dt * 16 + col], acc[dt][r]);

  // ---- completion semaphore: last chunk-block of graph g finalizes it ----
  __threadfence();                 // this block's atomics device-visible before increment
  __syncthreads();
  if (t == 0) lastflag = (atomicAdd((int*)(ws + OFF_DONE) + g, 1) == nch - 1);
  __syncthreads();
  if (!lastflag) return;
  __threadfence();                 // acquire: see all other blocks' contributions

  // ================== fused finalize for graph g (verified k_final body) =========
  {
    const float* sume = (const float*)(ws + OFF_SUMEXP);
    const float* WvT = (const float*)(ws + OFF_WVT);
    const float* WoT = (const float*)(ws + OFF_WOT);
    const float* F1T = (const float*)(ws + OFF_FC1T);
    const float* F2T = (const float*)(ws + OFF_FC2T);
    float* xb  = (float*)smem;          // [16][256]  16384 B
    float* cx  = xb + 16 * 256;         // [4][256]    4096 B
    float* fl  = cx + 4 * 256;          // [1024]      4096 B
    float* hh  = fl + 1024;             // [256]       1024 B
    float* inv = hh + 256;              // [16]          64 B   (25664 <= 37376)

    if (t < 16) inv[t] = 1.0f / sume[g * SH + t];
    __syncthreads();
    #pragma unroll
    for (int sh = 0; sh < 16; sh++)
      xb[sh * 256 + t] = accw[(size_t)g * (SH * D) + sh * D + t] * inv[sh];
    __syncthreads();

    const int h = t >> 6;
    {  // ctx = Wv_h @ xbar + bv
      float ca[4] = {0, 0, 0, 0};
      #pragma unroll 4
      for (int d = 0; d < 256; d++) {
        float wvd = WvT[(size_t)d * D + t];
        #pragma unroll
        for (int s = 0; s < 4; s++) ca[s] += wvd * xb[(s * 4 + h) * 256 + d];
      }
      float bv = inb[2 * D + t];
      #pragma unroll
      for (int s = 0; s < 4; s++) cx[s * 256 + t] = ca[s] + bv;
    }
    __syncthreads();
    {  // attended = Wo @ ctx + bo -> flat
      float aa[4] = {0, 0, 0, 0};
      #pragma unroll 4
      for (int d = 0; d < 256; d++) {
        float wod = WoT[(size_t)d * D + t];
        #pragma unroll
        for (int s = 0; s < 4; s++) aa[s] += wod * cx[s * 256 + d];
      }
      float bo = ob[t];
      #pragma unroll
      for (int s = 0; s < 4; s++) fl[s * 256 + t] = aa[s] + bo;
    }
    __syncthreads();
    {  // h = gelu(fc1 @ flat + b) — 4 partial chains for ILP
      float f1p[4] = {0, 0, 0, 0};
      #pragma unroll 2
      for (int k = 0; k < 256; k++) {
        #pragma unroll
        for (int p = 0; p < 4; p++)
          f1p[p] += F1T[(size_t)(p * 256 + k) * D + t] * fl[p * 256 + k];
      }
      float x = f1p[0] + f1p[1] + f1p[2] + f1p[3] + f1b[t];
      hh[t] = 0.5f * x * (1.0f + erff(x * 0.70710678118654752f));
    }
    __syncthreads();
    {  // out = fc2 @ h + b
      float f2a = 0.f, f2c = 0.f;
      #pragma unroll 4
      for (int d = 0; d < 256; d += 2) {
        f2a += F2T[(size_t)d * D + t] * hh[d];
        f2c += F2T[(size_t)(d + 1) * D + t] * hh[d + 1];
      }
      out[(size_t)g * D + t] = f2a + f2c + f2b[t];
    }
  }
}

extern "C" void kernel_launch(void* const* d_in, const int* in_sizes, int n_in,
                              void* d_out, int out_size, void* d_ws, size_t ws_size,
                              hipStream_t stream) {
  const float* nf    = (const float*)d_in[0];
  const int*   cnts  = (const int*)d_in[1];
  const float* seeds = (const float*)d_in[2];
  const float* inw   = (const float*)d_in[3];
  const float* inb   = (const float*)d_in[4];
  const float* ow    = (const float*)d_in[5];
  const float* obv   = (const float*)d_in[6];
  const float* f1w   = (const float*)d_in[7];
  const float* f1b   = (const float*)d_in[8];
  const float* f2w   = (const float*)d_in[9];
  const float* f2b   = (const float*)d_in[10];
  char* ws = (char*)d_ws;
  float* out = (float*)d_out;
  int N = in_sizes[0] / D;

  k_pre<<<512, 256, 0, stream>>>(seeds, inw, inb, cnts, ow, f1w, f2w, ws);
  int maxc = (N + CH - 1) / CH + 256;
  k_main<<<maxc, 256, 0, stream>>>(nf, inb, obv, f1b, f2b, ws, out);
}

// Round 5
// 442.200 us; speedup vs baseline: 1.7910x; 1.7910x over previous
//
#include <hip/hip_runtime.h>

#define D 256
#define SH 16
#define Ss 4
#define CH 256          // nodes per chunk (one block per chunk)
#define NT 64           // nodes per LDS tile
#define XS_STRIDE 272   // f16 per row (544 B); data in e<256, pad 256..271
#define WB_STRIDE 80    // f16 per row (160 B)

typedef _Float16 half8 __attribute__((ext_vector_type(8)));
typedef _Float16 half4 __attribute__((ext_vector_type(4)));
typedef float f32x4 __attribute__((ext_vector_type(4)));

// workspace layout (bytes)
#define OFF_AF16   ((size_t)0)         // a_f16[16][256]            8192
#define OFF_CM     ((size_t)8192)      // CM[16] f32 (= -6*||a||)
#define OFF_DESC   ((size_t)12544)     // int nchunks (+pad16), int4 desc[<=1295]
#define OFF_SUMEXP ((size_t)33280)     // [256][16] f32             16384
#define OFF_ACC    ((size_t)49664)     // [256][16][256] f32        4194304
#define OFF_WVT    ((size_t)4243968)   // WvT[256][256]
#define OFF_WOT    ((size_t)4506112)   // WoT[256][256]
#define OFF_FC1T   ((size_t)4768256)   // fc1T[1024][256]
#define OFF_FC2T   ((size_t)5816832)   // fc2T[256][256]

// ---------- K0: fused prep — zero + weight transposes + a/cm + chunk descriptors ----
__global__ void k_pre(const float* __restrict__ seeds,
                      const float* __restrict__ inw,
                      const float* __restrict__ inb,
                      const int* __restrict__ counts,
                      const float* __restrict__ ow,
                      const float* __restrict__ f1w,
                      const float* __restrict__ f2w,
                      char* __restrict__ ws) {
  __shared__ __align__(16) char smem[4352];
  const int t = threadIdx.x;
  const int b = blockIdx.x;

  // zero sumexp + acc (ordered before k_main by dispatch boundary)
  {
    f32x4* z = (f32x4*)(ws + OFF_SUMEXP);
    const int total4 = (16384 + 4194304) / 16;
    f32x4 zero = {0.f, 0.f, 0.f, 0.f};
    for (int i = b * 256 + t; i < total4; i += 512 * 256) z[i] = zero;
  }

  if (b < 448) {
    // ---- weight transposes (coalesced epilogue reads) ----
    const float* src; float* dst; int R, C, ti, tj;
    if (b < 64)       { src = inw + (size_t)512 * D; dst = (float*)(ws + OFF_WVT);  R = 256; C = 256;  int x = b;       tj = x / 8; ti = x % 8; }
    else if (b < 128) { src = ow;                    dst = (float*)(ws + OFF_WOT);  R = 256; C = 256;  int x = b - 64;  tj = x / 8; ti = x % 8; }
    else if (b < 192) { src = f2w;                   dst = (float*)(ws + OFF_FC2T); R = 256; C = 256;  int x = b - 128; tj = x / 8; ti = x % 8; }
    else              { src = f1w;                   dst = (float*)(ws + OFF_FC1T); R = 256; C = 1024; int x = b - 192; tj = x / 8; ti = x % 8; }
    float (*tl)[33] = (float(*)[33])smem;
    int tx = t & 31, ty = t >> 5;   // 32 x 8
    #pragma unroll
    for (int k = 0; k < 4; k++) {
      int r = ty + k * 8;
      tl[r][tx] = src[(size_t)(ti * 32 + r) * C + tj * 32 + tx];
    }
    __syncthreads();
    #pragma unroll
    for (int k = 0; k < 4; k++) {
      int r = ty + k * 8;
      dst[(size_t)(tj * 32 + r) * R + ti * 32 + tx] = tl[tx][r];
    }
  } else if (b < 464) {
    // ---- a[sh] = 0.125 * q_sh @ Wk_h ; CM[sh] = -6*||a||  (q computed inline) ----
    int sh = b - 448, s = sh >> 2, h = sh & 3;
    float* sd   = (float*)smem;     // seeds row s          [256]
    float* part = sd + 256;         // q partials [4][64]
    float* qh   = part + 256;       // q head slice          [64]
    float* red  = qh + 64;          // reduction             [256]
    sd[t] = seeds[s * D + t];
    __syncthreads();
    int j = t & 63, p = t >> 6;
    const float4* wq = (const float4*)(inw + (size_t)(h * 64 + j) * D + p * 64);
    float pa = 0.f;
    #pragma unroll
    for (int k4 = 0; k4 < 16; k4++) {
      float4 w4 = wq[k4];
      pa += w4.x * sd[p*64 + 4*k4] + w4.y * sd[p*64 + 4*k4 + 1]
          + w4.z * sd[p*64 + 4*k4 + 2] + w4.w * sd[p*64 + 4*k4 + 3];
    }
    part[p * 64 + j] = pa;
    __syncthreads();
    if (t < 64) qh[t] = part[t] + part[64 + t] + part[128 + t] + part[192 + t] + inb[h * 64 + t];
    __syncthreads();
    const float* wk = inw + (size_t)(D + h * 64) * D;   // Wk rows for head h
    float a = 0.f;
    #pragma unroll 8
    for (int d = 0; d < 64; d++) a += qh[d] * wk[(size_t)d * D + t];
    a *= 0.125f;
    ((_Float16*)(ws + OFF_AF16))[sh * D + t] = (_Float16)a;
    red[t] = a * a;
    __syncthreads();
    for (int st = 128; st > 0; st >>= 1) { if (t < st) red[t] += red[t + st]; __syncthreads(); }
    if (t == 0) ((float*)(ws + OFF_CM))[sh] = -6.0f * sqrtf(red[0]);
  } else if (b == 464) {
    // ---- chunk descriptors ----
    int* s1 = (int*)smem;
    int* s2 = s1 + 256;
    int cnt = counts[t];
    int nch = (cnt + CH - 1) / CH;
    s1[t] = cnt; s2[t] = nch;
    __syncthreads();
    for (int off = 1; off < 256; off <<= 1) {
      int a1 = (t >= off) ? s1[t - off] : 0;
      int a2 = (t >= off) ? s2[t - off] : 0;
      __syncthreads();
      s1[t] += a1; s2[t] += a2;
      __syncthreads();
    }
    int start = s1[t] - cnt, cb = s2[t] - nch;
    int4* desc = (int4*)(ws + OFF_DESC + 16);
    for (int jj = 0; jj < nch; jj++) {
      int nn = cnt - jj * CH; if (nn > CH) nn = CH;
      desc[cb + jj] = make_int4(t, start + jj * CH, nn, 0);
    }
    if (t == 255) *(int*)(ws + OFF_DESC) = s2[255];
  }
}

// ---------- K1: main single-sweep attention pass (T14 pipelined staging) ----------
// EXACT round-3 version (verified <157 us). LDS swizzle: within-row f16 offset e
// stored at e ^ (((row>>3)&3)<<4) -> accumulate gather conflict-free. Tile t+1's 16
// global_load_dwordx4 issued during tile t's LDS write, waited next iteration.
__launch_bounds__(256, 3)
__global__ void k_main(const float* __restrict__ nf, char* __restrict__ ws) {
  int nchunks = *(const int*)(ws + OFF_DESC);
  if ((int)blockIdx.x >= nchunks) return;
  int4 dsc = ((const int4*)(ws + OFF_DESC + 16))[blockIdx.x];
  int g = dsc.x, start = dsc.y, cnt = dsc.z;

  __shared__ _Float16 xs[NT * XS_STRIDE];   // node tile, f16, swizzled rows
  __shared__ _Float16 wb[SH * WB_STRIDE];   // softmax weights [sh][node]

  const int t = threadIdx.x;
  const int lane = t & 63, wv = t >> 6;
  const int col = lane & 15, q = lane >> 4;

  // persistent B-frags of a (score GEMM), 32 VGPRs
  const _Float16* af = (const _Float16*)(ws + OFF_AF16);
  half8 aw[8];
  #pragma unroll
  for (int kc = 0; kc < 8; kc++) aw[kc] = *(const half8*)(af + col * D + kc * 32 + q * 8);
  const float cmv = ((const float*)(ws + OFF_CM))[col];

  f32x4 acc[4] = {{0,0,0,0},{0,0,0,0},{0,0,0,0},{0,0,0,0}};  // [sh(4 rows)] x d-slice
  float dsum = 0.f;

  const int ntile = (cnt + NT - 1) / NT;
  float4 vr[16];

  // prologue: stage tile 0 into regs (row = p*4+wv, c4 = lane)
  #pragma unroll
  for (int p = 0; p < 16; p++) {
    int row = p * 4 + wv;
    vr[p] = make_float4(0.f, 0.f, 0.f, 0.f);
    if (row < cnt) vr[p] = ((const float4*)(nf + (size_t)(start + row) * D))[lane];
  }

  for (int tile = 0; tile < ntile; tile++) {
    const bool more = (tile + 1) < ntile;
    const int nbase = (tile + 1) * NT;
    // ---- convert + write tile t, immediately re-issue loads for tile t+1 ----
    #pragma unroll
    for (int p = 0; p < 16; p++) {
      int row = p * 4 + wv;
      float4 v = vr[p];
      half4 hv;
      hv[0] = (_Float16)v.x; hv[1] = (_Float16)v.y;
      hv[2] = (_Float16)v.z; hv[3] = (_Float16)v.w;
      int e = (lane * 4) ^ (((row >> 3) & 3) << 4);
      *(half4*)(xs + row * XS_STRIDE + e) = hv;
      if (more) {
        int nloc = nbase + row;
        vr[p] = make_float4(0.f, 0.f, 0.f, 0.f);
        if (nloc < cnt) vr[p] = ((const float4*)(nf + (size_t)(start + nloc) * D))[lane];
      }
    }
    __syncthreads();

    // ---- scores: S[16n x 16sh] per wave (wave w owns nodes w*16..+15) ----
    f32x4 sc = {0, 0, 0, 0};
    {
      int srow = wv * 16 + col;
      const _Float16* xrow = xs + srow * XS_STRIDE;
      int sxor = ((srow >> 3) & 3) << 4;
      #pragma unroll
      for (int kc = 0; kc < 8; kc++) {
        half8 xa = *(const half8*)(xrow + ((q * 8 + kc * 32) ^ sxor));
        sc = __builtin_amdgcn_mfma_f32_16x16x32_f16(xa, aw[kc], sc, 0, 0, 0);
      }
    }
    #pragma unroll
    for (int r = 0; r < 4; r++) {
      int nloc = wv * 16 + q * 4 + r;
      float arg = fminf(sc[r] + cmv, 10.f);
      float wj = (tile * NT + nloc < cnt) ? __expf(arg) : 0.f;
      _Float16 wh = (_Float16)wj;
      dsum += (float)wh;                    // denominator consistent with f16 numerator
      wb[col * WB_STRIDE + nloc] = wh;
    }
    __syncthreads();

    // ---- accumulate: acc[16sh x 64d-slice per wave] += w^T @ X ----
    // gather row = ks*32+q*8+jj -> ((row>>3)&3) == q -> xor is q<<4 (conflict-free)
    #pragma unroll
    for (int ks = 0; ks < 2; ks++) {
      half8 wa = *(const half8*)(wb + col * WB_STRIDE + ks * 32 + q * 8);
      #pragma unroll
      for (int dt = 0; dt < 4; dt++) {
        int dd = (wv * 64 + dt * 16 + col) ^ (q << 4);
        half8 xb;
        #pragma unroll
        for (int jj = 0; jj < 8; jj++) xb[jj] = xs[(ks * 32 + q * 8 + jj) * XS_STRIDE + dd];
        acc[dt] = __builtin_amdgcn_mfma_f32_16x16x32_f16(wa, xb, acc[dt], 0, 0, 0);
      }
    }
    __syncthreads();
  }

  // ---- chunk epilogue: denominators + weighted sums via device atomics ----
  dsum += __shfl_xor(dsum, 16);
  dsum += __shfl_xor(dsum, 32);
  if (q == 0) atomicAdd(((float*)(ws + OFF_SUMEXP)) + g * SH + col, dsum);
  float* accw = (float*)(ws + OFF_ACC);
  #pragma unroll
  for (int dt = 0; dt < 4; dt++)
    #pragma unroll
    for (int r = 0; r < 4; r++)
      atomicAdd(&accw[(size_t)(g * SH + q * 4 + r) * D + wv * 64 + dt * 16 + col], acc[dt][r]);
}

// ---------- K2: finalize, 1024 threads, 4-way split-K, 1 graph/block ----------
__global__ void k_final(const float* __restrict__ inb, const float* __restrict__ ob,
                        const float* __restrict__ f1b, const float* __restrict__ f2b,
                        const char* __restrict__ ws, float* __restrict__ out) {
  const int tid = threadIdx.x;      // 0..1023
  const int t = tid & 255;          // output index
  const int kk = tid >> 8;          // k-quarter 0..3
  const int g = blockIdx.x;
  const float* sume = (const float*)(ws + OFF_SUMEXP);
  const float* accw = (const float*)(ws + OFF_ACC);
  const float* WvT = (const float*)(ws + OFF_WVT);
  const float* WoT = (const float*)(ws + OFF_WOT);
  const float* F1T = (const float*)(ws + OFF_FC1T);
  const float* F2T = (const float*)(ws + OFF_FC2T);

  __shared__ float xb[16 * 256];
  __shared__ float cx[4 * 256];
  __shared__ float fl[1024];
  __shared__ float hh[256];
  __shared__ float inv[16];
  __shared__ float part[3 * 4 * 256];   // split-K reduction scratch

  if (tid < 16) inv[tid] = 1.0f / sume[g * SH + tid];
  __syncthreads();
  {  // xb load: one float4 per thread (64 float4 per sh-row)
    float4 v = ((const float4*)(accw + (size_t)g * (SH * D)))[tid];
    float iv = inv[tid >> 6];
    ((float4*)xb)[tid] = make_float4(v.x * iv, v.y * iv, v.z * iv, v.w * iv);
  }
  __syncthreads();

  const int h = t >> 6;
  {  // ctx = Wv_h @ xbar + bv   (each quarter does 64 of 256 k-steps)
    float ca[4] = {0, 0, 0, 0};
    #pragma unroll 4
    for (int d = 0; d < 64; d++) {
      int dd = kk * 64 + d;
      float wvd = WvT[(size_t)dd * D + t];
      #pragma unroll
      for (int s = 0; s < 4; s++) ca[s] += wvd * xb[(s * 4 + h) * 256 + dd];
    }
    if (kk) { for (int s = 0; s < 4; s++) part[(kk - 1) * 1024 + s * 256 + t] = ca[s]; }
    __syncthreads();
    if (!kk) {
      float bv = inb[2 * D + t];
      #pragma unroll
      for (int s = 0; s < 4; s++)
        cx[s * 256 + t] = ca[s] + part[s * 256 + t] + part[1024 + s * 256 + t]
                        + part[2048 + s * 256 + t] + bv;
    }
    __syncthreads();
  }
  {  // attended = Wo @ ctx + bo -> flat
    float aa[4] = {0, 0, 0, 0};
    #pragma unroll 4
    for (int d = 0; d < 64; d++) {
      int dd = kk * 64 + d;
      float wod = WoT[(size_t)dd * D + t];
      #pragma unroll
      for (int s = 0; s < 4; s++) aa[s] += wod * cx[s * 256 + dd];
    }
    if (kk) { for (int s = 0; s < 4; s++) part[(kk - 1) * 1024 + s * 256 + t] = aa[s]; }
    __syncthreads();
    if (!kk) {
      float bo = ob[t];
      #pragma unroll
      for (int s = 0; s < 4; s++)
        fl[s * 256 + t] = aa[s] + part[s * 256 + t] + part[1024 + s * 256 + t]
                        + part[2048 + s * 256 + t] + bo;
    }
    __syncthreads();
  }
  {  // h = gelu(fc1 @ flat + b)  (each quarter does 256 of 1024, 2 ILP chains)
    float f1p[2] = {0, 0};
    #pragma unroll 4
    for (int k2 = 0; k2 < 128; k2++) {
      int k = kk * 256 + k2;
      f1p[0] += F1T[(size_t)k * D + t] * fl[k];
      f1p[1] += F1T[(size_t)(k + 128) * D + t] * fl[k + 128];
    }
    float f1 = f1p[0] + f1p[1];
    if (kk) part[(kk - 1) * 256 + t] = f1;
    __syncthreads();
    if (!kk) {
      float x = f1 + part[t] + part[256 + t] + part[512 + t] + f1b[t];
      hh[t] = 0.5f * x * (1.0f + erff(x * 0.70710678118654752f));
    }
    __syncthreads();
  }
  {  // out = fc2 @ h + b
    float f2 = 0.f;
    #pragma unroll 4
    for (int d = 0; d < 64; d++) {
      int dd = kk * 64 + d;
      f2 += F2T[(size_t)dd * D + t] * hh[dd];
    }
    if (kk) part[(kk - 1) * 256 + t] = f2;
    __syncthreads();
    if (!kk) out[(size_t)g * D + t] = f2 + part[t] + part[256 + t] + part[512 + t] + f2b[t];
  }
}

extern "C" void kernel_launch(void* const* d_in, const int* in_sizes, int n_in,
                              void* d_out, int out_size, void* d_ws, size_t ws_size,
                              hipStream_t stream) {
  const float* nf    = (const float*)d_in[0];
  const int*   cnts  = (const int*)d_in[1];
  const float* seeds = (const float*)d_in[2];
  const float* inw   = (const float*)d_in[3];
  const float* inb   = (const float*)d_in[4];
  const float* ow    = (const float*)d_in[5];
  const float* obv   = (const float*)d_in[6];
  const float* f1w   = (const float*)d_in[7];
  const float* f1b   = (const float*)d_in[8];
  const float* f2w   = (const float*)d_in[9];
  const float* f2b   = (const float*)d_in[10];
  char* ws = (char*)d_ws;
  float* out = (float*)d_out;
  int N = in_sizes[0] / D;

  k_pre<<<512, 256, 0, stream>>>(seeds, inw, inb, cnts, ow, f1w, f2w, ws);
  int maxc = (N + CH - 1) / CH + 256;
  k_main<<<maxc, 256, 0, stream>>>(nf, ws);
  k_final<<<256, 1024, 0, stream>>>(inb, obv, f1b, f2b, ws, out);
}